// Round 1
// baseline (462.156 us; speedup 1.0000x reference)
//
#include <hip/hip_runtime.h>

#define NBATCH 4
#define L0C 4096          // 64*64
#define W0C 64
#define MCAND 20000
#define ANUM 64
#define CONF_ELEMS (NBATCH * L0C * L0C)   // 4*4096*4096 = 67108864

// ws layout: int maxm[NBATCH*L0C]  (64 KiB)
__global__ void init_kernel(int* __restrict__ maxm) {
    int i = blockIdx.x * blockDim.x + threadIdx.x;
    if (i < NBATCH * L0C) maxm[i] = -1;
}

// last-write-wins scatter == keep the max match index m per (b,i) slot
__global__ void scatter_kernel(const int* __restrict__ b_ids,
                               const int* __restrict__ i_ids,
                               int* __restrict__ maxm) {
    int m = blockIdx.x * blockDim.x + threadIdx.x;
    if (m < MCAND) {
        int b = b_ids[m];
        int i = i_ids[m];
        atomicMax(&maxm[b * L0C + i], m);
    }
}

// one block (256 threads) per batch: build conf grid in LDS, NMS mask,
// stable prefix over raster order, emit first-64 anchors tiled by cnt.
__global__ __launch_bounds__(256) void anchors_kernel(
        const int* __restrict__ maxm,
        const float* __restrict__ mconf,
        const int* __restrict__ j_ids,
        float* __restrict__ out) {
    __shared__ float conf_sh[L0C];
    __shared__ int cnt_sh[256];
    __shared__ int pref_sh[257];
    __shared__ int sel_sh[ANUM];

    const int b = blockIdx.x;
    const int t = threadIdx.x;

    // resolve scatter: conf = mconf[maxm] or 0
    #pragma unroll
    for (int k = 0; k < 16; ++k) {
        int s = t * 16 + k;
        int mm = maxm[b * L0C + s];
        conf_sh[s] = (mm >= 0) ? mconf[mm] : 0.0f;
    }
    __syncthreads();

    // 2x2 maxpool (stride 1, pad right/bottom with 0) local-max mask
    unsigned int bits = 0;
    int lc = 0;
    #pragma unroll
    for (int k = 0; k < 16; ++k) {
        int s = t * 16 + k;
        float c = conf_sh[s];
        int x = s & (W0C - 1);
        int y = s >> 6;
        float r  = (x < W0C - 1) ? conf_sh[s + 1]  : 0.0f;
        float d  = (y < W0C - 1) ? conf_sh[s + 64] : 0.0f;
        float dg = (x < W0C - 1 && y < W0C - 1) ? conf_sh[s + 65] : 0.0f;
        bool m = (c > 0.0f) && (c >= r) && (c >= d) && (c >= dg);
        if (m) { bits |= (1u << k); ++lc; }
    }
    cnt_sh[t] = lc;
    __syncthreads();

    if (t == 0) {
        int acc = 0;
        for (int i = 0; i < 256; ++i) { pref_sh[i] = acc; acc += cnt_sh[i]; }
        pref_sh[256] = acc;
    }
    __syncthreads();

    // scatter first-64 surviving flat indices (raster order)
    int rank = pref_sh[t];
    #pragma unroll
    for (int k = 0; k < 16; ++k) {
        if (bits & (1u << k)) {
            if (rank < ANUM) sel_sh[rank] = t * 16 + k;
            ++rank;
        }
    }
    const int cnt = pref_sh[256];
    __syncthreads();

    if (t < ANUM) {
        float v0 = 0.f, v1 = 0.f, v2 = 0.f, v3 = 0.f;
        if (cnt > 0) {
            int s = sel_sh[t % cnt];          // t%cnt < min(cnt,64) always
            int mm = maxm[b * L0C + s];        // >=0 since conf>0 there
            int j = j_ids[mm];
            v0 = (float)(s >> 6);
            v1 = (float)(s & (W0C - 1));
            v2 = (float)(j >> 6);
            v3 = (float)(j & (W0C - 1));
        }
        float* o = out + (b * ANUM + t) * 4;
        o[0] = v0; o[1] = v1; o[2] = v2; o[3] = v3;
    }
}

// 256 MiB passthrough copy, float4 vectorized grid-stride
__global__ __launch_bounds__(256) void copy_kernel(const float4* __restrict__ src,
                                                   float4* __restrict__ dst, int n4) {
    int i = blockIdx.x * blockDim.x + threadIdx.x;
    int stride = gridDim.x * blockDim.x;
    for (; i < n4; i += stride) dst[i] = src[i];
}

extern "C" void kernel_launch(void* const* d_in, const int* in_sizes, int n_in,
                              void* d_out, int out_size, void* d_ws, size_t ws_size,
                              hipStream_t stream) {
    const float* conf_matrix = (const float*)d_in[0];
    const float* mconf       = (const float*)d_in[1];
    const int*   b_ids       = (const int*)d_in[2];
    const int*   i_ids       = (const int*)d_in[3];
    const int*   j_ids       = (const int*)d_in[4];

    float* out = (float*)d_out;
    int*   maxm = (int*)d_ws;                 // NBATCH*L0C ints = 64 KiB

    init_kernel<<<(NBATCH * L0C + 255) / 256, 256, 0, stream>>>(maxm);
    scatter_kernel<<<(MCAND + 255) / 256, 256, 0, stream>>>(b_ids, i_ids, maxm);
    anchors_kernel<<<NBATCH, 256, 0, stream>>>(maxm, mconf, j_ids, out);

    const int n4 = CONF_ELEMS / 4;            // 16777216 float4
    float4* dst = (float4*)(out + NBATCH * ANUM * 4);   // +4096 B, 16B-aligned
    copy_kernel<<<2048, 256, 0, stream>>>((const float4*)conf_matrix, dst, n4);
}